// Round 2
// baseline (195.593 us; speedup 1.0000x reference)
//
#include <hip/hip_runtime.h>

// Chamfer loss via MFMA, N=4, P1=P2=8192, D=3, K=1.
// d2 = |x|^2 + |y|^2 - 2 x.y  ==  sum_k A[i][k]*B[j][k]  with K=16 (padded to 32)
// using fp16 hi/lo splits (exact up to ~1e-6):
//   A(pred): [xh0..2, xl0..2, xh0..2, pwh, pwl, 1, 1, xl0..2, 0x16]
//   B(targ): [-2yh0..2, -2yh0..2, -2yl0..2, 1, 1, qwh, qwl, -2yl0..2, 0x16]
// Slot pairing is k-permutation-invariant: A and B fragments are loaded with the
// SAME lane->slot pattern (16B at [pt][ (lane>>4)*8 ]), so whatever the HW k
// mapping is, the MFMA computes the slot-wise dot product.
// C/D layout (HW-verified): col = lane&15, row = (lane>>4)*4 + reg.
//
// chamfer_mfma: block = 4 waves; wave = 128 rows x 16 cols per j-step.
//   row-min -> rowacc[8][4] in VGPRs, block-end LDS combine -> rowpart[b][seg][row]
//   col-min -> per-lane tree + 2 shfl_xor -> colpart[b][rb][col]   (no loop barriers)
// chamfer_reduce: min over 4 seg slots (dir0) / 64 rb slots (dir1), clamp, scale, sum.

typedef _Float16 f16;
typedef _Float16 half8 __attribute__((ext_vector_type(8)));
typedef float f32x4 __attribute__((ext_vector_type(4)));

constexpr int N = 4;
constexpr int P = 8192;
constexpr int NSEG = 4;
constexpr int SEGC = P / NSEG;   // 2048
constexpr int BM = 128;          // rows per block
constexpr int RB = P / BM;       // 64 row blocks
constexpr float BIGV = 1e30f;

__global__ __launch_bounds__(256) void chamfer_prep(
    const float* __restrict__ pred, const float* __restrict__ targ,
    f16* __restrict__ apack, f16* __restrict__ bpack)
{
    const int idx = blockIdx.x * 256 + threadIdx.x;    // [0, N*P)
    const f16 one = (f16)1.0f;
    const half8 vz = {0, 0, 0, 0, 0, 0, 0, 0};
    {
        const float* s = pred + (size_t)idx * 3;
        const float x0 = s[0], x1 = s[1], x2 = s[2];
        const float pw = fmaf(x0, x0, fmaf(x1, x1, x2 * x2));
        const f16 h0 = (f16)x0, h1 = (f16)x1, h2 = (f16)x2;
        const f16 l0 = (f16)(x0 - (float)h0), l1 = (f16)(x1 - (float)h1), l2 = (f16)(x2 - (float)h2);
        const f16 wh = (f16)pw, wl = (f16)(pw - (float)wh);
        half8 v0 = {h0, h1, h2, l0, l1, l2, h0, h1};
        half8 v1 = {h2, wh, wl, one, one, l0, l1, l2};
        half8* dst = (half8*)(apack + (size_t)idx * 32);
        dst[0] = v0; dst[1] = v1; dst[2] = vz; dst[3] = vz;
    }
    {
        const float* s = targ + (size_t)idx * 3;
        const float y0 = s[0], y1 = s[1], y2 = s[2];
        const float qw = fmaf(y0, y0, fmaf(y1, y1, y2 * y2));
        const f16 g0 = (f16)y0, g1 = (f16)y1, g2 = (f16)y2;
        const f16 m0 = (f16)(y0 - (float)g0), m1 = (f16)(y1 - (float)g1), m2 = (f16)(y2 - (float)g2);
        const f16 n0 = (f16)(-2.0f * (float)g0), n1 = (f16)(-2.0f * (float)g1), n2 = (f16)(-2.0f * (float)g2);
        const f16 u0 = (f16)(-2.0f * (float)m0), u1 = (f16)(-2.0f * (float)m1), u2 = (f16)(-2.0f * (float)m2);
        const f16 qh = (f16)qw, ql = (f16)(qw - (float)qh);
        half8 v0 = {n0, n1, n2, n0, n1, n2, u0, u1};
        half8 v1 = {u2, one, one, qh, ql, u0, u1, u2};
        half8* dst = (half8*)(bpack + (size_t)idx * 32);
        dst[0] = v0; dst[1] = v1; dst[2] = vz; dst[3] = vz;
    }
}

__global__ __launch_bounds__(256, 4) void chamfer_mfma(
    const f16* __restrict__ apack, const f16* __restrict__ bpack,
    const int* __restrict__ lens, float* __restrict__ colpart,
    float* __restrict__ rowpart)
{
    const int seg = blockIdx.y;
    const int b   = blockIdx.x >> 6;           // RB = 64
    const int rb  = blockIdx.x & (RB - 1);
    const int L   = lens[b];
    const int c0  = seg * SEGC;
    const int tid = threadIdx.x;
    const int w    = tid >> 6;                 // wave 0..3 -> 16-col slot
    const int lane = tid & 63;
    const int q    = lane >> 4;                // quarter: k-group / row-group
    const int cc   = lane & 15;                // A-row (frag) / C-col

    float* rp = rowpart + ((size_t)b * NSEG + seg) * P + rb * BM;
    if (c0 >= L) {                             // block-uniform early out
        if (tid < BM) rp[tid] = BIGV;
        return;
    }

    __shared__ float red[BM][65];

    // A fragments for 8 row-tiles (loaded once; rows = rb*128 + it*16 + cc)
    const f16* ab = apack + (size_t)b * (P * 32);
    half8 afr[8];
    #pragma unroll
    for (int it = 0; it < 8; ++it)
        afr[it] = *(const half8*)(ab + ((size_t)(rb * BM + it * 16 + cc)) * 32 + q * 8);

    float rowacc[8][4];
    #pragma unroll
    for (int it = 0; it < 8; ++it)
        #pragma unroll
        for (int r = 0; r < 4; ++r) rowacc[it][r] = BIGV;

    const f16* bb = bpack + (size_t)b * (P * 32);
    const int Ll  = L - c0;
    const int Lloc = (Ll < SEGC) ? Ll : SEGC;
    const int njs  = (Lloc + 63) >> 6;         // block advances 64 cols per step

    float* cp = colpart + ((size_t)b * RB + rb) * P;
    const f32x4 zz = {0.f, 0.f, 0.f, 0.f};

    int colj = c0 + w * 16 + cc;               // this lane's column
    half8 bfr_n = *(const half8*)(bb + (size_t)colj * 32 + q * 8);

    for (int js = 0; js < njs; ++js) {
        const half8 bfr = bfr_n;
        {   // prefetch next step's B fragment (clamped; garbage unused)
            int cn = colj + 64;
            int cs = (cn < P) ? cn : 0;
            bfr_n = *(const half8*)(bb + (size_t)cs * 32 + q * 8);
        }

        f32x4 acc0[4], acc1[4];
        #pragma unroll
        for (int it = 0; it < 4; ++it)
            acc0[it] = __builtin_amdgcn_mfma_f32_16x16x32_f16(afr[it], bfr, zz, 0, 0, 0);
        float cm = BIGV;
        #pragma unroll
        for (int it = 0; it < 4; ++it)
            cm = fminf(cm, fminf(fminf(acc0[it][0], acc0[it][1]), fminf(acc0[it][2], acc0[it][3])));
        #pragma unroll
        for (int it = 0; it < 4; ++it)
            acc1[it] = __builtin_amdgcn_mfma_f32_16x16x32_f16(afr[4 + it], bfr, zz, 0, 0, 0);
        #pragma unroll
        for (int it = 0; it < 4; ++it)
            cm = fminf(cm, fminf(fminf(acc1[it][0], acc1[it][1]), fminf(acc1[it][2], acc1[it][3])));

        // col-min across the 4 quarters holding this col (rows 0..127 complete)
        cm = fminf(cm, __shfl_xor(cm, 16, 64));
        cm = fminf(cm, __shfl_xor(cm, 32, 64));
        if (q == 0) cp[colj] = cm;             // cols >= L written but never read

        // row-min accumulate (mask only on the boundary step; wave-uniform branch)
        if (colj - cc + 16 <= L) {
            #pragma unroll
            for (int it = 0; it < 4; ++it)
                #pragma unroll
                for (int r = 0; r < 4; ++r) {
                    rowacc[it][r]     = fminf(rowacc[it][r],     acc0[it][r]);
                    rowacc[4 + it][r] = fminf(rowacc[4 + it][r], acc1[it][r]);
                }
        } else {
            const bool val = colj < L;
            #pragma unroll
            for (int it = 0; it < 4; ++it)
                #pragma unroll
                for (int r = 0; r < 4; ++r) {
                    rowacc[it][r]     = fminf(rowacc[it][r],     val ? acc0[it][r] : BIGV);
                    rowacc[4 + it][r] = fminf(rowacc[4 + it][r], val ? acc1[it][r] : BIGV);
                }
        }
        colj += 64;
    }

    // block-end row-min combine: row = it*16 + q*4 + r, slot = w*16 + cc
    #pragma unroll
    for (int it = 0; it < 8; ++it)
        #pragma unroll
        for (int r = 0; r < 4; ++r)
            red[it * 16 + q * 4 + r][w * 16 + cc] = rowacc[it][r];
    __syncthreads();
    {
        const int row = tid >> 1, half = tid & 1;
        const float* rr = &red[row][half * 32];
        float v = rr[0];
        #pragma unroll
        for (int i = 1; i < 32; ++i) v = fminf(v, rr[i]);
        v = fminf(v, __shfl_xor(v, 1, 64));
        if (half == 0) rp[row] = v;
    }
}

__global__ __launch_bounds__(256) void chamfer_reduce(
    const float* __restrict__ colpart, const float* __restrict__ rowpart,
    const int* __restrict__ lens, float* __restrict__ out)
{
    const int item = blockIdx.x * 256 + threadIdx.x;   // 2*N*P = 65536
    const int dir = item >> 15;
    const int b   = (item >> 13) & (N - 1);
    const int p   = item & (P - 1);
    const int L   = lens[b];

    float c = 0.f;
    if (dir == 0) {        // pred->targ: min over NSEG row slots
        const float* base = rowpart + ((size_t)b * NSEG) * P + p;
        float v = base[0];
        #pragma unroll
        for (int s = 1; s < NSEG; ++s) v = fminf(v, base[(size_t)s * P]);
        c = fmaxf(v, 0.f) * (1.0f / ((float)P * (float)N));
    } else if (p < L) {    // targ->pred: min over RB col slots
        const float* base = colpart + (size_t)b * RB * P + p;
        float v = base[0];
        #pragma unroll 16
        for (int g = 1; g < RB; ++g) v = fminf(v, base[(size_t)g * P]);
        c = fmaxf(v, 0.f) / ((float)L * (float)N);
    }
    #pragma unroll
    for (int off = 32; off; off >>= 1) c += __shfl_down(c, off, 64);
    __shared__ float acc[4];
    if ((threadIdx.x & 63) == 0) acc[threadIdx.x >> 6] = c;
    __syncthreads();
    if (threadIdx.x == 0) atomicAdd(out, acc[0] + acc[1] + acc[2] + acc[3]);
}

extern "C" void kernel_launch(void* const* d_in, const int* in_sizes, int n_in,
                              void* d_out, int out_size, void* d_ws, size_t ws_size,
                              hipStream_t stream)
{
    const float* pred = (const float*)d_in[0];
    const float* targ = (const float*)d_in[1];
    const int*   lens = (const int*)d_in[2];
    float* out = (float*)d_out;
    char*  ws  = (char*)d_ws;

    // ws layout: apack 2MB | bpack 2MB | colpart 8MB | rowpart 512KB  (~12.5MB)
    f16*   apack   = (f16*)ws;
    f16*   bpack   = (f16*)(ws + (size_t)N * P * 32 * sizeof(f16));
    float* colpart = (float*)(ws + (size_t)2 * N * P * 32 * sizeof(f16));
    float* rowpart = (float*)(ws + (size_t)2 * N * P * 32 * sizeof(f16)
                                 + (size_t)N * RB * P * sizeof(float));

    hipMemsetAsync(out, 0, out_size * sizeof(float), stream);
    chamfer_prep<<<(N * P) / 256, 256, 0, stream>>>(pred, targ, apack, bpack);
    chamfer_mfma<<<dim3(N * RB, NSEG), 256, 0, stream>>>(apack, bpack, lens, colpart, rowpart);
    chamfer_reduce<<<(2 * N * P) / 256, 256, 0, stream>>>(colpart, rowpart, lens, out);
}

// Round 3
// 188.672 us; speedup vs baseline: 1.0367x; 1.0367x over previous
//
#include <hip/hip_runtime.h>

// Chamfer loss via MFMA, two symmetric row-min passes. N=4, P1=P2=8192, D=3, K=1.
// d2 = |x|^2+|y|^2-2x.y == sum_k A[i][k]*B[j][k], K=16 (padded to 32), fp16 hi/lo
// splits (exact products, fp32 accumulate):
//   row-style(p): [h0,h1,h2, l0,l1,l2, h0,h1 | h2, wh,wl, 1,1, l0,l1,l2 | 0...]
//   col-style(p): [-2h0..2, -2h0..2, -2l0,-2l1 | -2l2, 1,1, wh,wl, -2l0..2 | 0...]
// Slot pairing is k-permutation-invariant: A and B fragments are loaded with the
// SAME lane->slot pattern (16B at [pt][q*8]), verified working in round 1/2.
// C/D layout (HW-verified): col = lane&15, row = (lane>>4)*4 + reg.
//
// chamfer_pass (one dispatch, pass bit in swizzled block id):
//   pass 0: rows=pred(row-style), cols=targ(col-style) -> min over cols (cham_x)
//   pass 1: rows=targ(row-style), cols=pred(col-style) -> min over cols (cham_y)
//   wave = 128 rows x 16 cols/step; rows persist in VGPRs; hot loop has NO
//   cross-lane ops / stores / barriers: prefetched B-load + 8 MFMA + 32 fminf.
//   Block-end: two-phase LDS transpose (64x65, 16.6KB) -> part[pass][b][seg][row].
// chamfer_reduce: min over 8 seg slots per direction, clamp, scale, sum.

typedef _Float16 f16;
typedef _Float16 half8 __attribute__((ext_vector_type(8)));
typedef float f32x4 __attribute__((ext_vector_type(4)));

constexpr int N = 4;
constexpr int P = 8192;
constexpr int NSEG = 8;
constexpr int SEGC = P / NSEG;   // 1024
constexpr int BM = 128;          // rows per block
constexpr int RB = P / BM;       // 64 row blocks
constexpr float BIGV = 1e30f;

__global__ __launch_bounds__(256) void chamfer_prep(
    const float* __restrict__ pred, const float* __restrict__ targ,
    f16* __restrict__ rowP, f16* __restrict__ colP,
    f16* __restrict__ rowT, f16* __restrict__ colT)
{
    const int idx = blockIdx.x * 256 + threadIdx.x;    // [0, N*P)
    const f16 one = (f16)1.0f;
    const half8 vz = {0, 0, 0, 0, 0, 0, 0, 0};
    #pragma unroll
    for (int which = 0; which < 2; ++which) {
        const float* s = (which ? targ : pred) + (size_t)idx * 3;
        half8* rdst = (half8*)((which ? rowT : rowP) + (size_t)idx * 32);
        half8* cdst = (half8*)((which ? colT : colP) + (size_t)idx * 32);
        const float x0 = s[0], x1 = s[1], x2 = s[2];
        const float w = fmaf(x0, x0, fmaf(x1, x1, x2 * x2));
        const f16 h0 = (f16)x0, h1 = (f16)x1, h2 = (f16)x2;
        const f16 l0 = (f16)(x0 - (float)h0), l1 = (f16)(x1 - (float)h1), l2 = (f16)(x2 - (float)h2);
        const f16 wh = (f16)w, wl = (f16)(w - (float)wh);
        half8 r0 = {h0, h1, h2, l0, l1, l2, h0, h1};
        half8 r1 = {h2, wh, wl, one, one, l0, l1, l2};
        rdst[0] = r0; rdst[1] = r1; rdst[2] = vz; rdst[3] = vz;
        const f16 n0 = (f16)(-2.0f * (float)h0), n1 = (f16)(-2.0f * (float)h1), n2 = (f16)(-2.0f * (float)h2);
        const f16 u0 = (f16)(-2.0f * (float)l0), u1 = (f16)(-2.0f * (float)l1), u2 = (f16)(-2.0f * (float)l2);
        half8 c0v = {n0, n1, n2, n0, n1, n2, u0, u1};
        half8 c1v = {u2, one, one, wh, wl, u0, u1, u2};
        cdst[0] = c0v; cdst[1] = c1v; cdst[2] = vz; cdst[3] = vz;
    }
}

__global__ __launch_bounds__(256, 4) void chamfer_pass(
    const f16* __restrict__ rowP, const f16* __restrict__ colP,
    const f16* __restrict__ rowT, const f16* __restrict__ colT,
    const int* __restrict__ lens, float* __restrict__ part)
{
    // XCD-chunked bijective swizzle (4096 % 8 == 0): blocks sharing a B panel
    // (consecutive rb, same (pass,b,seg)) land on the same XCD's L2.
    const int H = blockIdx.x;
    const int Lid = (H & 7) * 512 + (H >> 3);
    const int rb   = Lid & (RB - 1);
    const int b    = (Lid >> 6) & (N - 1);
    const int seg  = (Lid >> 8) & (NSEG - 1);
    const int pass = Lid >> 11;

    const int L    = lens[b];
    const int Lcol = pass ? P : L;
    const int row0 = rb * BM;
    const int c0   = seg * SEGC;
    const int tid  = threadIdx.x;
    const int w    = tid >> 6;                 // wave: 16-col slot within 64-col step
    const int lane = tid & 63;
    const int q    = lane >> 4;                // k-group / C-row-group
    const int cc   = lane & 15;                // A-row (frag) / C-col

    float* wrow = part + (((size_t)pass * N + b) * NSEG + seg) * P + row0;

    if (pass && row0 >= L) return;             // padded target rows: unread
    if (c0 >= Lcol) {                          // no valid cols (pass 0 only)
        if (tid < BM) wrow[tid] = BIGV;
        return;
    }

    const f16* ab = (pass ? rowT : rowP) + (size_t)b * (P * 32);
    const f16* bb = (pass ? colP : colT) + (size_t)b * (P * 32);

    half8 afr[8];
    #pragma unroll
    for (int it = 0; it < 8; ++it)
        afr[it] = *(const half8*)(ab + (size_t)(row0 + it * 16 + cc) * 32 + q * 8);

    float rowacc[8][4];
    #pragma unroll
    for (int it = 0; it < 8; ++it)
        #pragma unroll
        for (int r = 0; r < 4; ++r) rowacc[it][r] = BIGV;

    const int Ll   = Lcol - c0;
    const int Lloc = (Ll < SEGC) ? Ll : SEGC;
    const int njs  = (Lloc + 63) >> 6;         // block advances 64 cols per step

    const f32x4 zz = {0.f, 0.f, 0.f, 0.f};
    int colj = c0 + w * 16 + cc;
    half8 bfr_n = *(const half8*)(bb + (size_t)colj * 32 + q * 8);

    for (int js = 0; js < njs; ++js) {
        const half8 bfr = bfr_n;
        {   // prefetch next step's fragment (clamped; last-step value unused)
            int cn = colj + 64;
            cn = (cn < P) ? cn : colj;
            bfr_n = *(const half8*)(bb + (size_t)cn * 32 + q * 8);
        }
        f32x4 acc[8];
        #pragma unroll
        for (int it = 0; it < 8; ++it)
            acc[it] = __builtin_amdgcn_mfma_f32_16x16x32_f16(afr[it], bfr, zz, 0, 0, 0);

        if (colj - cc + 16 <= Lcol) {          // wave-uniform: whole 16-col slot valid
            #pragma unroll
            for (int it = 0; it < 8; ++it)
                #pragma unroll
                for (int r = 0; r < 4; ++r)
                    rowacc[it][r] = fminf(rowacc[it][r], acc[it][r]);
        } else {                               // boundary step (pass 0 only)
            const bool val = colj < Lcol;
            #pragma unroll
            for (int it = 0; it < 8; ++it)
                #pragma unroll
                for (int r = 0; r < 4; ++r)
                    rowacc[it][r] = fminf(rowacc[it][r], val ? acc[it][r] : BIGV);
        }
        colj += 64;
    }

    // block-end combine: two phases of 64 rows through a 16.6KB LDS transpose.
    // phase ph covers global rows ph*64 + [0,64): row = (it-4ph)*16 + q*4 + r.
    __shared__ float red[64][65];
    #pragma unroll
    for (int ph = 0; ph < 2; ++ph) {
        if (ph) __syncthreads();               // phase-0 readers done before overwrite
        #pragma unroll
        for (int it = 0; it < 4; ++it)
            #pragma unroll
            for (int r = 0; r < 4; ++r)
                red[it * 16 + q * 4 + r][w * 16 + cc] = rowacc[4 * ph + it][r];
        __syncthreads();
        const int row = tid >> 2, grp = tid & 3;
        const float* rr = &red[row][grp * 16];
        float v = rr[0];
        #pragma unroll
        for (int i = 1; i < 16; ++i) v = fminf(v, rr[i]);
        v = fminf(v, __shfl_xor(v, 1, 64));
        v = fminf(v, __shfl_xor(v, 2, 64));
        if (grp == 0) wrow[ph * 64 + row] = v;
    }
}

__global__ __launch_bounds__(256) void chamfer_reduce(
    const float* __restrict__ part, const int* __restrict__ lens,
    float* __restrict__ out)
{
    const int item = blockIdx.x * 256 + threadIdx.x;   // 2*N*P = 65536
    const int dir = item >> 15;
    const int b   = (item >> 13) & (N - 1);
    const int p   = item & (P - 1);
    const int L   = lens[b];

    float c = 0.f;
    if (dir == 0) {        // pred->targ
        const float* base = part + ((size_t)b * NSEG) * P + p;
        float v = base[0];
        #pragma unroll
        for (int s = 1; s < NSEG; ++s) v = fminf(v, base[(size_t)s * P]);
        c = fmaxf(v, 0.f) * (1.0f / ((float)P * (float)N));
    } else if (p < L) {    // targ->pred
        const float* base = part + (((size_t)N + b) * NSEG) * P + p;
        float v = base[0];
        #pragma unroll
        for (int s = 1; s < NSEG; ++s) v = fminf(v, base[(size_t)s * P]);
        c = fmaxf(v, 0.f) / ((float)L * (float)N);
    }
    #pragma unroll
    for (int off = 32; off; off >>= 1) c += __shfl_down(c, off, 64);
    __shared__ float acc[4];
    if ((threadIdx.x & 63) == 0) acc[threadIdx.x >> 6] = c;
    __syncthreads();
    if (threadIdx.x == 0) atomicAdd(out, acc[0] + acc[1] + acc[2] + acc[3]);
}

extern "C" void kernel_launch(void* const* d_in, const int* in_sizes, int n_in,
                              void* d_out, int out_size, void* d_ws, size_t ws_size,
                              hipStream_t stream)
{
    const float* pred = (const float*)d_in[0];
    const float* targ = (const float*)d_in[1];
    const int*   lens = (const int*)d_in[2];
    float* out = (float*)d_out;
    char*  ws  = (char*)d_ws;

    // ws: rowP | colP | rowT | colT (2MB each) | part 2*N*NSEG*P floats (2MB)
    const size_t packb = (size_t)N * P * 32 * sizeof(f16);
    f16*   rowP = (f16*)ws;
    f16*   colP = (f16*)(ws + packb);
    f16*   rowT = (f16*)(ws + 2 * packb);
    f16*   colT = (f16*)(ws + 3 * packb);
    float* part = (float*)(ws + 4 * packb);

    hipMemsetAsync(out, 0, out_size * sizeof(float), stream);
    chamfer_prep<<<(N * P) / 256, 256, 0, stream>>>(pred, targ, rowP, colP, rowT, colT);
    chamfer_pass<<<2 * N * RB * NSEG, 256, 0, stream>>>(rowP, colP, rowT, colT, lens, part);
    chamfer_reduce<<<(2 * N * P) / 256, 256, 0, stream>>>(part, lens, out);
}

// Round 4
// 111.850 us; speedup vs baseline: 1.7487x; 1.6868x over previous
//
#include <hip/hip_runtime.h>

// Chamfer loss via MFMA, two symmetric row-min passes. N=4, P1=P2=8192, D=3, K=1.
// d2 = |x|^2+|y|^2-2x.y == sum_k A[i][k]*B[j][k], K=16 (padded to 32), fp16 hi/lo
// splits (exact products, fp32 accumulate):
//   row-style(p): [h0,h1,h2, l0,l1,l2, h0,h1 | h2, wh,wl, 1,1, l0,l1,l2 | 0...]
//   col-style(p): [-2h0..2, -2h0..2, -2l0,-2l1 | -2l2, 1,1, wh,wl, -2l0..2 | 0...]
// Slot pairing is k-permutation-invariant (A and B fragments use the SAME
// lane->slot pattern: 16B at [pt][q*8]) — verified rounds 1-3 (absmax 0).
// C/D layout (HW-verified): col = lane&15, row = (lane>>4)*4 + reg.
//
// Round-4 schedule: wave-autonomous. Each wave owns 64 rows (4 A-frags,
// persistent in VGPRs) and sweeps 64 cols/step: 4 B-frags -> 16 independent
// MFMA + 64 fmin per step, ping-pong prefetch (4 loads in flight, no register
// copies). NO LDS, NO barriers anywhere; row-min closes per-wave with
// shfl_xor once per block. Early-exit waves just return.

typedef _Float16 f16;
typedef _Float16 half8 __attribute__((ext_vector_type(8)));
typedef float f32x4 __attribute__((ext_vector_type(4)));

constexpr int N = 4;
constexpr int P = 8192;
constexpr int NSEG = 8;
constexpr int SEGC = P / NSEG;     // 1024
constexpr int BROWS = 256;         // rows per block (4 waves x 64)
constexpr int RBLK = P / BROWS;    // 32
constexpr float BIGV = 1e30f;

__global__ __launch_bounds__(256) void chamfer_prep(
    const float* __restrict__ pred, const float* __restrict__ targ,
    f16* __restrict__ rowP, f16* __restrict__ colP,
    f16* __restrict__ rowT, f16* __restrict__ colT)
{
    const int idx = blockIdx.x * 256 + threadIdx.x;    // [0, N*P)
    const f16 one = (f16)1.0f;
    const half8 vz = {0, 0, 0, 0, 0, 0, 0, 0};
    #pragma unroll
    for (int which = 0; which < 2; ++which) {
        const float* s = (which ? targ : pred) + (size_t)idx * 3;
        half8* rdst = (half8*)((which ? rowT : rowP) + (size_t)idx * 32);
        half8* cdst = (half8*)((which ? colT : colP) + (size_t)idx * 32);
        const float x0 = s[0], x1 = s[1], x2 = s[2];
        const float w = fmaf(x0, x0, fmaf(x1, x1, x2 * x2));
        const f16 h0 = (f16)x0, h1 = (f16)x1, h2 = (f16)x2;
        const f16 l0 = (f16)(x0 - (float)h0), l1 = (f16)(x1 - (float)h1), l2 = (f16)(x2 - (float)h2);
        const f16 wh = (f16)w, wl = (f16)(w - (float)wh);
        half8 r0 = {h0, h1, h2, l0, l1, l2, h0, h1};
        half8 r1 = {h2, wh, wl, one, one, l0, l1, l2};
        rdst[0] = r0; rdst[1] = r1; rdst[2] = vz; rdst[3] = vz;
        const f16 n0 = (f16)(-2.0f * (float)h0), n1 = (f16)(-2.0f * (float)h1), n2 = (f16)(-2.0f * (float)h2);
        const f16 u0 = (f16)(-2.0f * (float)l0), u1 = (f16)(-2.0f * (float)l1), u2 = (f16)(-2.0f * (float)l2);
        half8 c0v = {n0, n1, n2, n0, n1, n2, u0, u1};
        half8 c1v = {u2, one, one, wh, wl, u0, u1, u2};
        cdst[0] = c0v; cdst[1] = c1v; cdst[2] = vz; cdst[3] = vz;
    }
}

__global__ __launch_bounds__(256) void chamfer_pass(
    const f16* __restrict__ rowP, const f16* __restrict__ colP,
    const f16* __restrict__ rowT, const f16* __restrict__ colT,
    const int* __restrict__ lens, float* __restrict__ part)
{
    // XCD-chunked bijective swizzle (2048 % 8 == 0): the 32 rb-blocks sharing a
    // B panel (same pass,b,seg) land on one XCD's L2 (~512KB of panels/XCD).
    const int H   = blockIdx.x;
    const int Lid = (H & 7) * 256 + (H >> 3);
    const int rb   = Lid & (RBLK - 1);
    const int b    = (Lid >> 5) & (N - 1);
    const int seg  = (Lid >> 8) & (NSEG - 1);
    const int pass = Lid >> 11;
    // note: bits [5:7]=b? -- careful: RBLK=32 (5 bits), N=4 (2 bits), NSEG=8 (3)
    // Lid = rb | b<<5 | seg<<7 | pass<<10
    const int segf = (Lid >> 7) & (NSEG - 1);
    const int passf = Lid >> 10;

    const int L    = lens[b];
    const int Lcol = passf ? P : L;
    const int tid  = threadIdx.x;
    const int w    = tid >> 6;
    const int lane = tid & 63;
    const int q    = lane >> 4;               // k-group / C-row-group
    const int cc   = lane & 15;               // A-row (frag) / C-col
    const int row0 = rb * BROWS + w * 64;     // wave's 64 rows
    const int c0   = segf * SEGC;

    float* brow = part + (((size_t)passf * N + b) * NSEG + segf) * P + rb * BROWS;

    if (c0 >= Lcol) {                         // pass0 only: whole block invalid cols
        brow[tid] = BIGV;
        return;
    }
    if (passf && row0 >= L) return;           // padded target rows: never read

    const f16* ab = (passf ? rowT : rowP) + (size_t)b * (P * 32);
    const f16* bb = (passf ? colP : colT) + (size_t)b * (P * 32);

    half8 afr[4];
    #pragma unroll
    for (int it = 0; it < 4; ++it)
        afr[it] = *(const half8*)(ab + (size_t)(row0 + it * 16 + cc) * 32 + q * 8);

    float rowacc[4][4];
    #pragma unroll
    for (int it = 0; it < 4; ++it)
        #pragma unroll
        for (int r = 0; r < 4; ++r) rowacc[it][r] = BIGV;

    const int Ll   = Lcol - c0;
    const int Lloc = (Ll < SEGC) ? Ll : SEGC;
    int njs        = (Lloc + 63) >> 6;        // 64-col steps for this wave

    const f32x4 zz = {0.f, 0.f, 0.f, 0.f};
    const f16* bptr = bb + (size_t)cc * 32 + q * 8;   // per-lane base
    int cbase = c0;

    half8 b0[4], b1[4];
    #pragma unroll
    for (int f = 0; f < 4; ++f)
        b0[f] = *(const half8*)(bptr + (size_t)cbase * 32 + f * 512);

    auto STEP = [&](half8 (&cur)[4], half8 (&nxt)[4]) {
        const int cn = (cbase + 64 < P) ? (cbase + 64) : cbase;  // clamped prefetch
        #pragma unroll
        for (int f = 0; f < 4; ++f)
            nxt[f] = *(const half8*)(bptr + (size_t)cn * 32 + f * 512);
        if (cbase + 64 <= Lcol) {             // wave-uniform: all 64 cols valid
            #pragma unroll
            for (int f = 0; f < 4; ++f)
                #pragma unroll
                for (int it = 0; it < 4; ++it) {
                    const f32x4 d = __builtin_amdgcn_mfma_f32_16x16x32_f16(afr[it], cur[f], zz, 0, 0, 0);
                    #pragma unroll
                    for (int r = 0; r < 4; ++r)
                        rowacc[it][r] = fminf(rowacc[it][r], d[r]);
                }
        } else {                              // boundary step (pass 0 only)
            #pragma unroll
            for (int f = 0; f < 4; ++f) {
                const bool val = (cbase + f * 16 + cc) < Lcol;
                #pragma unroll
                for (int it = 0; it < 4; ++it) {
                    const f32x4 d = __builtin_amdgcn_mfma_f32_16x16x32_f16(afr[it], cur[f], zz, 0, 0, 0);
                    #pragma unroll
                    for (int r = 0; r < 4; ++r)
                        rowacc[it][r] = fminf(rowacc[it][r], val ? d[r] : BIGV);
                }
            }
        }
        cbase += 64;
    };

    while (njs >= 2) { STEP(b0, b1); STEP(b1, b0); njs -= 2; }
    if (njs) STEP(b0, b1);

    // wave-local row-min close: min over the 16 cc lanes, then float4 store.
    float* wrow = brow + w * 64;
    #pragma unroll
    for (int it = 0; it < 4; ++it) {
        #pragma unroll
        for (int r = 0; r < 4; ++r) {
            float v = rowacc[it][r];
            v = fminf(v, __shfl_xor(v, 1, 64));
            v = fminf(v, __shfl_xor(v, 2, 64));
            v = fminf(v, __shfl_xor(v, 4, 64));
            v = fminf(v, __shfl_xor(v, 8, 64));
            rowacc[it][r] = v;
        }
        if (cc == 0) {
            f32x4 o = {rowacc[it][0], rowacc[it][1], rowacc[it][2], rowacc[it][3]};
            *(f32x4*)(wrow + it * 16 + q * 4) = o;   // row = it*16 + q*4 + r
        }
    }
}

__global__ __launch_bounds__(256) void chamfer_reduce(
    const float* __restrict__ part, const int* __restrict__ lens,
    float* __restrict__ out)
{
    const int item = blockIdx.x * 256 + threadIdx.x;   // 2*N*P = 65536
    const int dir = item >> 15;
    const int b   = (item >> 13) & (N - 1);
    const int p   = item & (P - 1);
    const int L   = lens[b];

    float c = 0.f;
    if (dir == 0) {        // pred->targ
        const float* base = part + ((size_t)b * NSEG) * P + p;
        float v = base[0];
        #pragma unroll
        for (int s = 1; s < NSEG; ++s) v = fminf(v, base[(size_t)s * P]);
        c = fmaxf(v, 0.f) * (1.0f / ((float)P * (float)N));
    } else if (p < L) {    // targ->pred
        const float* base = part + (((size_t)N + b) * NSEG) * P + p;
        float v = base[0];
        #pragma unroll
        for (int s = 1; s < NSEG; ++s) v = fminf(v, base[(size_t)s * P]);
        c = fmaxf(v, 0.f) / ((float)L * (float)N);
    }
    #pragma unroll
    for (int off = 32; off; off >>= 1) c += __shfl_down(c, off, 64);
    __shared__ float acc[4];
    if ((threadIdx.x & 63) == 0) acc[threadIdx.x >> 6] = c;
    __syncthreads();
    if (threadIdx.x == 0) atomicAdd(out, acc[0] + acc[1] + acc[2] + acc[3]);
}

extern "C" void kernel_launch(void* const* d_in, const int* in_sizes, int n_in,
                              void* d_out, int out_size, void* d_ws, size_t ws_size,
                              hipStream_t stream)
{
    const float* pred = (const float*)d_in[0];
    const float* targ = (const float*)d_in[1];
    const int*   lens = (const int*)d_in[2];
    float* out = (float*)d_out;
    char*  ws  = (char*)d_ws;

    // ws: rowP | colP | rowT | colT (2MB each) | part 2*N*NSEG*P floats (2MB)
    const size_t packb = (size_t)N * P * 32 * sizeof(f16);
    f16*   rowP = (f16*)ws;
    f16*   colP = (f16*)(ws + packb);
    f16*   rowT = (f16*)(ws + 2 * packb);
    f16*   colT = (f16*)(ws + 3 * packb);
    float* part = (float*)(ws + 4 * packb);

    hipMemsetAsync(out, 0, out_size * sizeof(float), stream);
    chamfer_prep<<<(N * P) / 256, 256, 0, stream>>>(pred, targ, rowP, colP, rowT, colT);
    chamfer_pass<<<2 * N * RBLK * NSEG, 256, 0, stream>>>(rowP, colP, rowT, colT, lens, part);
    chamfer_reduce<<<(2 * N * P) / 256, 256, 0, stream>>>(part, lens, out);
}